// Round 9
// baseline (404.355 us; speedup 1.0000x reference)
//
#include <hip/hip_runtime.h>
#include <hip/hip_bf16.h>
#include <stdint.h>

#define DIMV 1910
#define KP   1920                 // padded K — multiple of 64
#define NT   30                   // K tiles of 64 per m-tile
#define TT   120                  // total tiles (4 m-tiles x NT)
#define PHI_F  1.6180339887498949f
#define BETA_F 0.3819660112501051f

typedef __attribute__((ext_vector_type(4))) float f32x4;
typedef __attribute__((ext_vector_type(8))) short bf16x8;
typedef __attribute__((ext_vector_type(8))) unsigned short u16x8;

__device__ __forceinline__ void gl16(const void* g, void* l) {
    __builtin_amdgcn_global_load_lds(
        (const __attribute__((address_space(1))) void*)(uintptr_t)g,
        (__attribute__((address_space(3))) void*)(uint32_t)(uintptr_t)l,
        16, 0, 0);
}

// Fused prep: even blocks convert x fp32 -> bf16 [M][1920]; odd blocks scatter
// COO atomics into Wd (overlapped: conv is BW-bound, scatter latency-bound).
__global__ void k_prep(const float* __restrict__ x, unsigned short* __restrict__ xb, int total8,
                       const int* __restrict__ ridx, const int* __restrict__ cidx,
                       const float* __restrict__ vals, float* __restrict__ Wd, int nz) {
    const int tid  = threadIdx.x;
    const int half = (int)gridDim.x >> 1;
    const int b    = (int)blockIdx.x >> 1;
    const int stride = half * 256;
    if ((blockIdx.x & 1) == 0) {
        for (int i = b * 256 + tid; i < total8; i += stride) {
            int v = i * 8;
            int row = v / KP;
            int col = v - row * KP;
            u16x8 o;
            if (col + 8 <= DIMV) {
                const float2* s = (const float2*)(x + (size_t)row * DIMV + col);
                float2 f0 = s[0], f1 = s[1], f2 = s[2], f3 = s[3];
                float f[8] = {f0.x, f0.y, f1.x, f1.y, f2.x, f2.y, f3.x, f3.y};
#pragma unroll
                for (int j = 0; j < 8; ++j) {
                    __hip_bfloat16 bb = __float2bfloat16(f[j]);
                    o[j] = *reinterpret_cast<unsigned short*>(&bb);
                }
            } else {
#pragma unroll
                for (int j = 0; j < 8; ++j) {
                    int c = col + j;
                    float fv = (c < DIMV) ? x[(size_t)row * DIMV + c] : 0.f;
                    __hip_bfloat16 bb = __float2bfloat16(fv);
                    o[j] = *reinterpret_cast<unsigned short*>(&bb);
                }
            }
            *(u16x8*)(xb + (size_t)v) = o;
        }
    } else {
        for (int i = b * 256 + tid; i < nz; i += stride)
            atomicAdd(Wd + (size_t)ridx[i] * DIMV + cidx[i], vals[i]);
    }
}

// W' = W + PHI*I, [1920 rows][1920 cols] bf16
__global__ void k_build_w(const float* __restrict__ Wd, unsigned short* __restrict__ Wb, int total8) {
    int stride = gridDim.x * blockDim.x;
    for (int i = blockIdx.x * blockDim.x + threadIdx.x; i < total8; i += stride) {
        int v = i * 8;
        int n = v / KP;
        int k = v - n * KP;
        u16x8 o;
#pragma unroll
        for (int j = 0; j < 8; ++j) {
            int kk = k + j;
            float fv = (n < DIMV && kk < DIMV) ? Wd[(size_t)n * DIMV + kk] : 0.f;
            if (kk == n && n < DIMV) fv += PHI_F;
            __hip_bfloat16 b = __float2bfloat16(fv);
            o[j] = *reinterpret_cast<unsigned short*>(&b);
        }
        *(u16x8*)(Wb + (size_t)v) = o;
    }
}

// C[m][n] = BETA * sum_k A[m][k] * B[n][k];  A = xb bf16 [32768][1920]
// Tile 256x256, BK=64, 512 threads (8 waves: 2M x 4N), per-wave 128x64.
// PERSISTENT flat tile loop t=0..119. A 2-buf + B 2-buf LDS (128KB).
// Pipelined phases (2/tile, 2 barriers/tile). Phase invariants (race-free by
// construction — the r8 failure was reads gated only by the reading wave's own
// vmcnt; here every ds_read follows a barrier preceded by ALL waves' drain):
//   phase p: s_barrier
//            issue next-phase ds_reads (12) + (ph1 only) stage A/B(t+2) gl16s
//            sched_barrier; MFMA(regs read in phase p-1) [overlaps reads+loads]
//            ph0: vmcnt(0)  -- drains A(t+1),B(t+1) staged at (t-1,ph1),
//                              >=1.5 MFMA-clusters old -> stall-free
//            ph1: vmcnt(8)  -- keeps A(t+2),B(t+2) in flight
//            lgkmcnt(0)     -- this phase's reads complete (free: ~1 cluster
//                              old) => next phase's gl16 can't clobber a
//                              buffer any wave is still reading
// Buffer safety at 2-deep: stage at (t,ph1) overwrites tile-t data, whose last
// read (kk1) was issued at (t,ph0) and retired by (t,ph0)'s lgkmcnt(0)+barrier.
// XCD-disjoint A: bmg=bid&31, bn=bid>>5. Swizzle as r2-r7 (verified, 0 confl).
__global__ __launch_bounds__(512, 2) void k_gemm(const short* __restrict__ A,
                                                 const short* __restrict__ B,
                                                 float* __restrict__ C) {
    __shared__ char lds[131072];   // A: 2x32KB @ 0/32768; B: 2x32KB @ 65536/98304

    const int bid = blockIdx.x;
    const int bmg = bid & 31;            // XCD-private A row group (bmg%8 == XCD)
    const int bn  = bid >> 5;            // 0..7 N column

    const int tid = threadIdx.x;
    const int w   = tid >> 6;
    const int l   = tid & 63;
    const int wm  = w >> 2;              // 0..1 (M)
    const int wn  = w & 3;               // 0..3 (N)
    const int fr  = l & 15;
    const int q   = l >> 4;              // 0..3

    // ---- staging source (pre-swizzled), linear LDS dest ----
    const int    srow = tid >> 3;                       // 0..63 row within a sweep
    const size_t KPB  = (size_t)KP * 2;                 // 3840 bytes/row
    const int    swz  = ((tid & 7) ^ (srow & 7)) * 16;
    const char*  bSrc = (const char*)B + (size_t)(bn * 256 + srow) * KPB + swz;
    const size_t sweep = (size_t)64 * KPB;
    char* stDst = lds + tid * 16;

    // ---- fragment read offsets (swizzled slots) ----
    const int co0  = ((q    ) ^ (fr & 7)) * 16;         // kk=0
    const int co1  = ((4 + q) ^ (fr & 7)) * 16;         // kk=1
    const int aOff = (wm * 128 + fr) * 128;             // + mi*2048, mi=0..7
    const int bOff = (wn * 64 + fr) * 128;              // + ni*2048, ni=0..3

    f32x4 acc[8][4] = {};
    bf16x8 aP0[8], aP1[8], bR0[4], bR1[4];   // ping-pong register banks (static names)

#define STAGE_A(src, kk_, slot, s) gl16((src) + (size_t)(s) * sweep + (size_t)(kk_) * 128, stDst + (slot) + (s) * 8192)
#define STAGE_B(kk_, slot, s)      gl16(bSrc  + (size_t)(s) * sweep + (size_t)(kk_) * 128, stDst + 65536 + (slot) + (s) * 8192)
#define MM(bank, bb)                                                             \
    _Pragma("unroll")                                                            \
    for (int mi = 0; mi < 8; ++mi)                                               \
        _Pragma("unroll")                                                        \
        for (int ni = 0; ni < 4; ++ni)                                           \
            acc[mi][ni] = __builtin_amdgcn_mfma_f32_16x16x32_bf16((bank)[mi], (bb)[ni], acc[mi][ni], 0, 0, 0);

    const char* aSrc0 = (const char*)A + (size_t)(bmg * 256 + srow) * KPB + swz;
    const size_t mstep = (size_t)8192 * KPB;

    // ---- prologue: A(0),B(0)->slot0; A(1),B(1)->slot1; drain tile0, keep tile1 ----
#pragma unroll
    for (int s = 0; s < 4; ++s) STAGE_A(aSrc0, 0, 0, s);
#pragma unroll
    for (int s = 0; s < 4; ++s) STAGE_B(0, 0, s);
#pragma unroll
    for (int s = 0; s < 4; ++s) STAGE_A(aSrc0, 1, 32768, s);
#pragma unroll
    for (int s = 0; s < 4; ++s) STAGE_B(1, 32768, s);
    asm volatile("s_waitcnt vmcnt(8)" ::: "memory");
    __builtin_amdgcn_s_barrier();
    __builtin_amdgcn_sched_barrier(0);
    // bank for tile-0 kk0 (own reads; compiler auto-waits before first MFMA use)
#pragma unroll
    for (int mi = 0; mi < 8; ++mi) aP0[mi] = *(const bf16x8*)(lds + aOff + mi * 2048 + co0);
#pragma unroll
    for (int ni = 0; ni < 4; ++ni) bR0[ni] = *(const bf16x8*)(lds + 65536 + bOff + ni * 2048 + co0);

    int bo  = 0;                         // slot byte offset of tile t ((t%2)*32768)
    int k2  = 2;                         // (t+2) % NT  (k-index staged this tile)
    int tkR = 0, mtR = 0;                // k-index / m-tile of tile t
    const char* aStage = aSrc0;          // A stage base (m-tile of t+2)

    for (int t = 0; t < TT; ++t) {
        const int nbo = bo ^ 32768;
        const char* pa  = lds + bo + aOff;
        const char* pb  = lds + 65536 + bo + bOff;
        const char* paN = lds + nbo + aOff;
        const char* pbN = lds + 65536 + nbo + bOff;
        const bool haveN = (t + 1 < TT);
        const bool have2 = (t + 2 < TT);

        // ======== phase 0: read kk1 bank | MFMA kk0 | drain tile t+1 ========
        __builtin_amdgcn_s_barrier();
        __builtin_amdgcn_sched_barrier(0);
#pragma unroll
        for (int mi = 0; mi < 8; ++mi) aP1[mi] = *(const bf16x8*)(pa + mi * 2048 + co1);
#pragma unroll
        for (int ni = 0; ni < 4; ++ni) bR1[ni] = *(const bf16x8*)(pb + ni * 2048 + co1);
        __builtin_amdgcn_sched_barrier(0);
        __builtin_amdgcn_s_setprio(1);
        MM(aP0, bR0)
        __builtin_amdgcn_s_setprio(0);
        asm volatile("s_waitcnt vmcnt(0)" ::: "memory");    // A(t+1),B(t+1) in LDS (staged 1.5 clusters ago)
        asm volatile("s_waitcnt lgkmcnt(0)" ::: "memory");  // this phase's reads retired
        __builtin_amdgcn_sched_barrier(0);

        // ======== phase 1: read tile(t+1) kk0 bank | stage tile(t+2) | MFMA kk1 ========
        __builtin_amdgcn_s_barrier();
        __builtin_amdgcn_sched_barrier(0);
        if (haveN) {
#pragma unroll
            for (int mi = 0; mi < 8; ++mi) aP0[mi] = *(const bf16x8*)(paN + mi * 2048 + co0);
#pragma unroll
            for (int ni = 0; ni < 4; ++ni) bR0[ni] = *(const bf16x8*)(pbN + ni * 2048 + co0);
        }
        if (have2) {
            // overwrite slot bo (tile t): kk1 reads retired at phase 0's lgkmcnt(0)+barrier
            STAGE_A(aStage, k2, bo, 0); STAGE_A(aStage, k2, bo, 1);
            STAGE_A(aStage, k2, bo, 2); STAGE_A(aStage, k2, bo, 3);
            STAGE_B(k2, bo, 0); STAGE_B(k2, bo, 1);
            STAGE_B(k2, bo, 2); STAGE_B(k2, bo, 3);
        }
        __builtin_amdgcn_sched_barrier(0);
        __builtin_amdgcn_s_setprio(1);
        MM(aP1, bR1)
        __builtin_amdgcn_s_setprio(0);
        asm volatile("s_waitcnt vmcnt(8)" ::: "memory");    // keep tile(t+2)'s 8 loads in flight
        asm volatile("s_waitcnt lgkmcnt(0)" ::: "memory");  // phase-1 reads retired
        __builtin_amdgcn_sched_barrier(0);

        // ---- m-tile epilogue: issue stores (drained by next phase-0 vmcnt(0)) ----
        if (tkR == NT - 1) {
            const int bm    = mtR * 32 + bmg;
            const int grow0 = bm * 256 + wm * 128 + q * 4;
            const int gcol0 = bn * 256 + wn * 64 + fr;
#pragma unroll
            for (int ei = 0; ei < 8; ++ei) {
#pragma unroll
                for (int ni = 0; ni < 4; ++ni) {
                    int gcol = gcol0 + ni * 16;
                    if (gcol < DIMV) {
                        size_t base = (size_t)(grow0 + ei * 16) * DIMV + gcol;
#pragma unroll
                        for (int r = 0; r < 4; ++r)
                            C[base + (size_t)r * DIMV] = BETA_F * acc[ei][ni][r];
                    }
                }
            }
            if (haveN) {
#pragma unroll
                for (int ei = 0; ei < 8; ++ei)
#pragma unroll
                    for (int ni = 0; ni < 4; ++ni)
                        acc[ei][ni] = (f32x4)(0.f);
            }
            tkR = 0; ++mtR;
        } else ++tkR;

        // rotate
        bo = nbo;
        if (++k2 == NT) { k2 = 0; aStage += mstep; }
    }
#undef STAGE_A
#undef STAGE_B
#undef MM
}

extern "C" void kernel_launch(void* const* d_in, const int* in_sizes, int n_in,
                              void* d_out, int out_size, void* d_ws, size_t ws_size,
                              hipStream_t stream) {
    const float* x    = (const float*)d_in[0];
    const int*   widx = (const int*)d_in[1];
    const float* wval = (const float*)d_in[2];
    float* out = (float*)d_out;

    const int nz = in_sizes[2];
    const int M  = in_sizes[0] / DIMV;      // 32768

    const size_t xb_bytes = (size_t)M * KP * 2;          // 125,829,120
    const size_t wb_bytes = (size_t)2048 * KP * 2;       //   7,864,320
    const size_t wd_bytes = (size_t)DIMV * DIMV * 4;     //  14,592,400
    char* ws = (char*)d_ws;
    unsigned short* xb = (unsigned short*)ws;
    unsigned short* Wb = (unsigned short*)(ws + xb_bytes);
    float*          Wd = (float*)(ws + xb_bytes + wb_bytes);
    if (ws_size < xb_bytes + wb_bytes + wd_bytes) return;

    hipMemsetAsync(Wd, 0, wd_bytes, stream);
    k_prep<<<2048, 256, 0, stream>>>(x, xb, M * KP / 8, widx, widx + nz, wval, Wd, nz);
    k_build_w<<<1800, 256, 0, stream>>>(Wd, Wb, KP * KP / 8);
    k_gemm<<<256, 512, 0, stream>>>((const short*)xb, (const short*)Wb, out);
}